// Round 9
// baseline (292.494 us; speedup 1.0000x reference)
//
#include <hip/hip_runtime.h>

// Problem: N=4096, D=1024, C=1000, T=32
//   h = x @ W^T  (4096 x 2000), mu = h[:, :1000], logvar = h[:, 1000:]
//   sigma = exp(0.5*logvar)
//   eps = jax.random.normal(key(42), (32,4096,1000))  -- threefry2x32, bit-exact
//   prob = mean_t softmax(mu + sigma*eps), out0 = exp(prob), out1 = sigma

typedef __attribute__((ext_vector_type(8))) _Float16 f16x8;
typedef __attribute__((ext_vector_type(4))) float f32x4;
typedef __attribute__((ext_vector_type(2))) float f32x2;

#define NC_TOT  4096000
#define H_HALF  65536000u   // half of T*N*C = 131072000

// ---------------- fp32 -> fp16 (RNE) ----------------
__device__ __forceinline__ unsigned short f2h(float f) {
  _Float16 h = (_Float16)f;
  return __builtin_bit_cast(unsigned short, h);
}

__global__ __launch_bounds__(256) void convert_kernel(
    const float* __restrict__ x, const float* __restrict__ W,
    unsigned short* __restrict__ xh, unsigned short* __restrict__ wh) {
  int qid = blockIdx.x * 256 + threadIdx.x;
  if (qid < 1048576) {                        // x: 4096*1024/4
    float4 v = ((const float4*)x)[qid];
    ((ushort4*)xh)[qid] = make_ushort4(f2h(v.x), f2h(v.y), f2h(v.z), f2h(v.w));
  } else {
    int q = qid - 1048576;                    // padded W quad index, < 524288
    int row = q >> 8;
    ushort4 o;
    if (row < 2000) {
      float4 v = ((const float4*)W)[q];
      o = make_ushort4(f2h(v.x), f2h(v.y), f2h(v.z), f2h(v.w));
    } else {
      o = make_ushort4(0, 0, 0, 0);
    }
    ((ushort4*)wh)[q] = o;
  }
}

// ---------------- fp16 MFMA GEMM: 128x128, L2-resident XCD regions ----------------
// r8 post-mortem: K-loop streams 256 MB of tile re-reads -> L3-BW-bound
// (~4.6 TB/s). Fix: 8(by) x 8(bx) region per XCD -> working set 2+2 MB fits
// the 4 MiB XCD L2; re-reads become L2 hits (36.9 TB/s).
#define BK 32

typedef __attribute__((address_space(3))) unsigned char lds_byte;
typedef __attribute__((address_space(1))) unsigned char glb_byte;

__device__ __forceinline__ void glds16(const unsigned short* g, unsigned short* l) {
  __builtin_amdgcn_global_load_lds((const glb_byte*)g, (lds_byte*)l, 16, 0, 0);
}

__global__ __launch_bounds__(256) void gemm_kernel(
    const unsigned short* __restrict__ Ah,    // [4096][1024] fp16 bits
    const unsigned short* __restrict__ Bh,    // [2048][1024] fp16 bits, padded
    float* __restrict__ mu,                   // [4096][1000]
    float* __restrict__ sigma_out) {          // d_out + NC_TOT
  const int K = 1024;
  __shared__ unsigned short As[128 * BK];     // 8 KB
  __shared__ unsigned short Bs[128 * BK];     // 8 KB

  // XCD regions: consecutive ids round-robin XCDs (id&7). XCD q owns
  // by in [ (q>>1)*8, +8 ), bx in [ (q&1)*8, +8 ) -- 64 blocks, all
  // co-resident (2/CU x 32 CU), streaming the same kk-slices together.
  int id  = blockIdx.x;                 // 0..511
  int xcd = id & 7;
  int r   = id >> 3;                    // 0..63
  int by  = (xcd >> 1) * 8 + (r >> 3);  // 0..31
  int bx  = (xcd & 1) * 8 + (r & 7);    // 0..15

  int tid  = threadIdx.x;
  int w    = tid >> 6;
  int lane = tid & 63;
  int wr   = (w >> 1) * 64;
  int wc   = (w & 1) * 64;
  int lrow = lane & 15;
  int kq   = lane >> 4;

  f32x4 acc[4][4];
  for (int i = 0; i < 4; i++)
    for (int j = 0; j < 4; j++) acc[i][j] = (f32x4){0.f, 0.f, 0.f, 0.f};

  int srow = w * 16 + (lane >> 2);
  int scol = (lane & 3) * 8;
  const unsigned short* Ap = Ah + (by * 128 + srow) * K + scol;
  const unsigned short* Bp = Bh + (bx * 128 + srow) * K + scol;
  unsigned short* lA = As + w * 512;
  unsigned short* lB = Bs + w * 512;

  for (int kk = 0; kk < K; kk += BK) {
    __syncthreads();
    glds16(Ap + kk,            lA);
    glds16(Ap + kk + 64 * K,   lA + 2048);
    glds16(Bp + kk,            lB);
    glds16(Bp + kk + 64 * K,   lB + 2048);
    __syncthreads();

    f16x8 a[4], b[4];
    for (int i = 0; i < 4; i++)
      a[i] = *(const f16x8*)(As + (wr + i * 16 + lrow) * BK + kq * 8);
    for (int j = 0; j < 4; j++)
      b[j] = *(const f16x8*)(Bs + (wc + j * 16 + lrow) * BK + kq * 8);
    for (int i = 0; i < 4; i++)
      for (int j = 0; j < 4; j++)
        acc[i][j] = __builtin_amdgcn_mfma_f32_16x16x32_f16(a[i], b[j], acc[i][j], 0, 0, 0);
  }

  // C/D layout: col = lane&15 (N), row = (lane>>4)*4 + reg (M)
  int orow0 = by * 128 + wr + (lane >> 4) * 4;
  int ocol0 = bx * 128 + wc + (lane & 15);
  for (int i = 0; i < 4; i++) {
    for (int j = 0; j < 4; j++) {
      int c = ocol0 + j * 16;
      for (int v = 0; v < 4; v++) {
        int r2 = orow0 + i * 16 + v;
        float val = acc[i][j][v];
        if (c < 1000)       mu[r2 * 1000 + c] = val;
        else if (c < 2000)  sigma_out[r2 * 1000 + (c - 1000)] = __expf(0.5f * val);
      }
    }
  }
}

// ---------------- threefry2x32, key = (0, 42) ----------------
__device__ __forceinline__ void threefry(unsigned x0, unsigned x1,
                                         unsigned& o0, unsigned& o1) {
  const unsigned ks1 = 42u;
  const unsigned ks2 = 0x1BD11BDAu ^ 42u;
#define TF_RND(r) { x0 += x1; x1 = (x1 << (r)) | (x1 >> (32 - (r))); x1 ^= x0; }
  x1 += ks1;
  TF_RND(13) TF_RND(15) TF_RND(26) TF_RND(6)
  x0 += ks1;  x1 += ks2 + 1u;
  TF_RND(17) TF_RND(29) TF_RND(16) TF_RND(24)
  x0 += ks2;  x1 += 2u;
  TF_RND(13) TF_RND(15) TF_RND(26) TF_RND(6)
  x1 += ks1 + 3u;
  TF_RND(17) TF_RND(29) TF_RND(16) TF_RND(24)
  x0 += ks1;  x1 += ks2 + 4u;
  TF_RND(13) TF_RND(15) TF_RND(26) TF_RND(6)
  x0 += ks2;  x1 += 5u;
#undef TF_RND
  o0 = x0; o1 = x1;
}

__device__ __forceinline__ float erfinv_big(float x, float w) {
  float v = __fsqrt_rn(w) - 3.0f;
  float p = -0.000200214257f;
  p = fmaf(p, v, 0.000100950558f);
  p = fmaf(p, v, 0.00134934322f);
  p = fmaf(p, v, -0.00367342844f);
  p = fmaf(p, v, 0.00573950773f);
  p = fmaf(p, v, -0.0076224613f);
  p = fmaf(p, v, 0.00943887047f);
  p = fmaf(p, v, 1.00167406f);
  p = fmaf(p, v, 2.83297682f);
  return 1.41421356f * (p * x);
}

__device__ __forceinline__ f32x2 splat2(float c) { return (f32x2){c, c}; }

__device__ __forceinline__ f32x2 normal2(f32x2 x) {
  f32x2 t = __builtin_elementwise_fma(-x, x, splat2(1.0f));
  f32x2 lg;
  lg.x = __builtin_amdgcn_logf(t.x);
  lg.y = __builtin_amdgcn_logf(t.y);
  f32x2 w = lg * splat2(-0.69314718f);
  f32x2 v = w - splat2(2.5f);
  f32x2 p = splat2(2.81022636e-08f);
  p = __builtin_elementwise_fma(p, v, splat2(3.43273939e-07f));
  p = __builtin_elementwise_fma(p, v, splat2(-3.5233877e-06f));
  p = __builtin_elementwise_fma(p, v, splat2(-4.39150654e-06f));
  p = __builtin_elementwise_fma(p, v, splat2(0.00021858087f));
  p = __builtin_elementwise_fma(p, v, splat2(-0.00125372503f));
  p = __builtin_elementwise_fma(p, v, splat2(-0.00417768164f));
  p = __builtin_elementwise_fma(p, v, splat2(0.246640727f));
  p = __builtin_elementwise_fma(p, v, splat2(1.50140941f));
  f32x2 r = (p * x) * splat2(1.41421356f);
  if (w.x >= 5.0f) r.x = erfinv_big(x.x, w.x);   // rare (~0.34%/sample)
  if (w.y >= 5.0f) r.y = erfinv_big(x.y, w.y);
  return r;
}

__device__ __forceinline__ f32x2 bits_to_u2(unsigned b0, unsigned b1) {
  f32x2 f;
  f.x = __builtin_bit_cast(float, (b0 >> 9) | 0x3f800000u);
  f.y = __builtin_bit_cast(float, (b1 >> 9) | 0x3f800000u);
  f = f - splat2(1.0f);
  return __builtin_elementwise_fma(f, splat2(2.0f), splat2(-0.99999994f));
}

// ---------------- sampling (round-2 structure, best measured) ----------------
__global__ __launch_bounds__(256) void sample_kernel(
    const float* __restrict__ mu,      // ws
    const float* __restrict__ sigma,   // d_out + NC
    float* __restrict__ out0) {        // d_out
  int n    = blockIdx.x;
  int tid  = threadIdx.x;
  int lane = tid & 63, w = tid >> 6;
  __shared__ float pbuf[4][1024];

  int cb = n * 1000;
  float muv[16], sgv[16], prob[16];
#pragma unroll
  for (int j = 0; j < 16; j++) {
    int c = j * 64 + lane;
    bool val = (c < 1000);
    muv[j] = val ? mu[cb + c]    : 0.f;
    sgv[j] = val ? sigma[cb + c] : 0.f;
    prob[j] = 0.f;
  }

  f32x2 e[16];
#pragma unroll 1
  for (int it = 0; it < 4; it++) {
    int t = w * 4 + it;
    unsigned ib = (unsigned)(t * 4096000 + cb) + (unsigned)lane;
    f32x2 s = splat2(0.f);
#pragma unroll
    for (int j = 0; j < 16; j++) {
      unsigned i0 = ib + (unsigned)(j * 64);
      unsigned o0, o1;
      threefry(i0, i0 + H_HALF, o0, o1);
      f32x2 eps = normal2(bits_to_u2(o0, o1));
      f32x2 lg = __builtin_elementwise_fma(splat2(sgv[j]), eps, splat2(muv[j]));
      f32x2 ev;
      ev.x = __expf(lg.x);                       // sample t
      ev.y = __expf(lg.y);                       // sample t+16
      if (j == 15) {                             // classes >= 1000 are padding
        ev.x = (lane < 40) ? ev.x : 0.f;
        ev.y = (lane < 40) ? ev.y : 0.f;
      }
      e[j] = ev;
      s = s + ev;
    }
#pragma unroll
    for (int m = 1; m < 64; m <<= 1) {
      s.x += __shfl_xor(s.x, m, 64);
      s.y += __shfl_xor(s.y, m, 64);
    }
    float rA = 1.0f / s.x, rB = 1.0f / s.y;
#pragma unroll
    for (int j = 0; j < 16; j++)
      prob[j] = fmaf(e[j].x, rA, fmaf(e[j].y, rB, prob[j]));
  }

#pragma unroll
  for (int j = 0; j < 16; j++)
    pbuf[w][j * 64 + lane] = prob[j];
  __syncthreads();
#pragma unroll
  for (int k = 0; k < 4; k++) {
    int c = tid + k * 256;
    if (c < 1000) {
      float sm = pbuf[0][c] + pbuf[1][c] + pbuf[2][c] + pbuf[3][c];
      out0[cb + c] = __expf(sm * 0.03125f);
    }
  }
}

// ---------------- launch ----------------
extern "C" void kernel_launch(void* const* d_in, const int* in_sizes, int n_in,
                              void* d_out, int out_size, void* d_ws, size_t ws_size,
                              hipStream_t stream) {
  const float* x = (const float*)d_in[0];   // 4096*1024
  const float* W = (const float*)d_in[1];   // 2000*1024
  float* out = (float*)d_out;               // [mu_out | sigma], each 4096000

  unsigned short* xh = (unsigned short*)d_ws;                        //  8,388,608 B
  unsigned short* wh = (unsigned short*)((char*)d_ws + 8388608);     //  4,194,304 B
  float*          mu = (float*)((char*)d_ws + 12582912);             // 16,384,000 B
  float* sigma = out + NC_TOT;

  convert_kernel<<<6144, 256, 0, stream>>>(x, W, xh, wh);
  gemm_kernel<<<512, 256, 0, stream>>>(xh, wh, mu, sigma);
  sample_kernel<<<4096, 256, 0, stream>>>(mu, sigma, out);
}

// Round 10
// 290.609 us; speedup vs baseline: 1.0065x; 1.0065x over previous
//
#include <hip/hip_runtime.h>

// Problem: N=4096, D=1024, C=1000, T=32
//   h = x @ W^T  (4096 x 2000), mu = h[:, :1000], logvar = h[:, 1000:]
//   sigma = exp(0.5*logvar)
//   eps = jax.random.normal(key(42), (32,4096,1000))  -- threefry2x32, bit-exact
//   prob = mean_t softmax(mu + sigma*eps), out0 = exp(prob), out1 = sigma

typedef __attribute__((ext_vector_type(8))) _Float16 f16x8;
typedef __attribute__((ext_vector_type(4))) float f32x4;
typedef __attribute__((ext_vector_type(2))) float f32x2;

#define NC_TOT  4096000
#define H_HALF  65536000u   // half of T*N*C = 131072000

// ---------------- fp32 -> fp16 (RNE) ----------------
__device__ __forceinline__ unsigned short f2h(float f) {
  _Float16 h = (_Float16)f;
  return __builtin_bit_cast(unsigned short, h);
}

__device__ __forceinline__ uint4 pack8(float4 a, float4 b) {
  uint4 o;
  o.x = (unsigned)f2h(a.x) | ((unsigned)f2h(a.y) << 16);
  o.y = (unsigned)f2h(a.z) | ((unsigned)f2h(a.w) << 16);
  o.z = (unsigned)f2h(b.x) | ((unsigned)f2h(b.y) << 16);
  o.w = (unsigned)f2h(b.z) | ((unsigned)f2h(b.w) << 16);
  return o;
}

// One thread per 8 floats: 2x float4 load, 1x 16B store (best coalescing).
// x: 524288 octs; W padded to 2048 rows: 262144 octs. 3072 blocks x 256.
__global__ __launch_bounds__(256) void convert_kernel(
    const float* __restrict__ x, const float* __restrict__ W,
    unsigned short* __restrict__ xh, unsigned short* __restrict__ wh) {
  int oid = blockIdx.x * 256 + threadIdx.x;   // oct index
  if (oid < 524288) {                         // x: 4096*1024/8
    float4 a = ((const float4*)x)[oid * 2];
    float4 b = ((const float4*)x)[oid * 2 + 1];
    ((uint4*)xh)[oid] = pack8(a, b);
  } else {
    int q = oid - 524288;                     // W oct, < 262144
    int row = q >> 7;                         // (q*8)>>10
    uint4 o;
    if (row < 2000) {
      float4 a = ((const float4*)W)[q * 2];
      float4 b = ((const float4*)W)[q * 2 + 1];
      o = pack8(a, b);
    } else {
      o = make_uint4(0, 0, 0, 0);
    }
    ((uint4*)wh)[q] = o;
  }
}

// ---------------- fp16 MFMA GEMM: 128x128, L2-resident XCD regions (r9) ----------------
// K-loop re-reads are served by the per-XCD L2: each XCD owns an 8(by) x 8(bx)
// region -> working set 2+2 MB < 4 MiB L2. Measured r9: rest-time 77 -> 59 us.
#define BK 32

typedef __attribute__((address_space(3))) unsigned char lds_byte;
typedef __attribute__((address_space(1))) unsigned char glb_byte;

__device__ __forceinline__ void glds16(const unsigned short* g, unsigned short* l) {
  __builtin_amdgcn_global_load_lds((const glb_byte*)g, (lds_byte*)l, 16, 0, 0);
}

__global__ __launch_bounds__(256) void gemm_kernel(
    const unsigned short* __restrict__ Ah,    // [4096][1024] fp16 bits
    const unsigned short* __restrict__ Bh,    // [2048][1024] fp16 bits, padded
    float* __restrict__ mu,                   // [4096][1000]
    float* __restrict__ sigma_out) {          // d_out + NC_TOT
  const int K = 1024;
  __shared__ unsigned short As[128 * BK];     // 8 KB
  __shared__ unsigned short Bs[128 * BK];     // 8 KB

  int id  = blockIdx.x;                 // 0..511
  int xcd = id & 7;
  int r   = id >> 3;                    // 0..63
  int by  = (xcd >> 1) * 8 + (r >> 3);  // 0..31
  int bx  = (xcd & 1) * 8 + (r & 7);    // 0..15

  int tid  = threadIdx.x;
  int w    = tid >> 6;
  int lane = tid & 63;
  int wr   = (w >> 1) * 64;
  int wc   = (w & 1) * 64;
  int lrow = lane & 15;
  int kq   = lane >> 4;

  f32x4 acc[4][4];
  for (int i = 0; i < 4; i++)
    for (int j = 0; j < 4; j++) acc[i][j] = (f32x4){0.f, 0.f, 0.f, 0.f};

  int srow = w * 16 + (lane >> 2);
  int scol = (lane & 3) * 8;
  const unsigned short* Ap = Ah + (by * 128 + srow) * K + scol;
  const unsigned short* Bp = Bh + (bx * 128 + srow) * K + scol;
  unsigned short* lA = As + w * 512;
  unsigned short* lB = Bs + w * 512;

  for (int kk = 0; kk < K; kk += BK) {
    __syncthreads();
    glds16(Ap + kk,            lA);
    glds16(Ap + kk + 64 * K,   lA + 2048);
    glds16(Bp + kk,            lB);
    glds16(Bp + kk + 64 * K,   lB + 2048);
    __syncthreads();

    f16x8 a[4], b[4];
    for (int i = 0; i < 4; i++)
      a[i] = *(const f16x8*)(As + (wr + i * 16 + lrow) * BK + kq * 8);
    for (int j = 0; j < 4; j++)
      b[j] = *(const f16x8*)(Bs + (wc + j * 16 + lrow) * BK + kq * 8);
    for (int i = 0; i < 4; i++)
      for (int j = 0; j < 4; j++)
        acc[i][j] = __builtin_amdgcn_mfma_f32_16x16x32_f16(a[i], b[j], acc[i][j], 0, 0, 0);
  }

  // C/D layout: col = lane&15 (N), row = (lane>>4)*4 + reg (M)
  int orow0 = by * 128 + wr + (lane >> 4) * 4;
  int ocol0 = bx * 128 + wc + (lane & 15);
  for (int i = 0; i < 4; i++) {
    for (int j = 0; j < 4; j++) {
      int c = ocol0 + j * 16;
      for (int v = 0; v < 4; v++) {
        int r2 = orow0 + i * 16 + v;
        float val = acc[i][j][v];
        if (c < 1000)       mu[r2 * 1000 + c] = val;
        else if (c < 2000)  sigma_out[r2 * 1000 + (c - 1000)] = __expf(0.5f * val);
      }
    }
  }
}

// ---------------- threefry2x32, key = (0, 42) ----------------
__device__ __forceinline__ void threefry(unsigned x0, unsigned x1,
                                         unsigned& o0, unsigned& o1) {
  const unsigned ks1 = 42u;
  const unsigned ks2 = 0x1BD11BDAu ^ 42u;
#define TF_RND(r) { x0 += x1; x1 = (x1 << (r)) | (x1 >> (32 - (r))); x1 ^= x0; }
  x1 += ks1;
  TF_RND(13) TF_RND(15) TF_RND(26) TF_RND(6)
  x0 += ks1;  x1 += ks2 + 1u;
  TF_RND(17) TF_RND(29) TF_RND(16) TF_RND(24)
  x0 += ks2;  x1 += 2u;
  TF_RND(13) TF_RND(15) TF_RND(26) TF_RND(6)
  x1 += ks1 + 3u;
  TF_RND(17) TF_RND(29) TF_RND(16) TF_RND(24)
  x0 += ks1;  x1 += ks2 + 4u;
  TF_RND(13) TF_RND(15) TF_RND(26) TF_RND(6)
  x0 += ks2;  x1 += 5u;
#undef TF_RND
  o0 = x0; o1 = x1;
}

__device__ __forceinline__ float erfinv_big(float x, float w) {
  float v = __fsqrt_rn(w) - 3.0f;
  float p = -0.000200214257f;
  p = fmaf(p, v, 0.000100950558f);
  p = fmaf(p, v, 0.00134934322f);
  p = fmaf(p, v, -0.00367342844f);
  p = fmaf(p, v, 0.00573950773f);
  p = fmaf(p, v, -0.0076224613f);
  p = fmaf(p, v, 0.00943887047f);
  p = fmaf(p, v, 1.00167406f);
  p = fmaf(p, v, 2.83297682f);
  return 1.41421356f * (p * x);
}

__device__ __forceinline__ f32x2 splat2(float c) { return (f32x2){c, c}; }

__device__ __forceinline__ f32x2 normal2(f32x2 x) {
  f32x2 t = __builtin_elementwise_fma(-x, x, splat2(1.0f));
  f32x2 lg;
  lg.x = __builtin_amdgcn_logf(t.x);
  lg.y = __builtin_amdgcn_logf(t.y);
  f32x2 w = lg * splat2(-0.69314718f);
  f32x2 v = w - splat2(2.5f);
  f32x2 p = splat2(2.81022636e-08f);
  p = __builtin_elementwise_fma(p, v, splat2(3.43273939e-07f));
  p = __builtin_elementwise_fma(p, v, splat2(-3.5233877e-06f));
  p = __builtin_elementwise_fma(p, v, splat2(-4.39150654e-06f));
  p = __builtin_elementwise_fma(p, v, splat2(0.00021858087f));
  p = __builtin_elementwise_fma(p, v, splat2(-0.00125372503f));
  p = __builtin_elementwise_fma(p, v, splat2(-0.00417768164f));
  p = __builtin_elementwise_fma(p, v, splat2(0.246640727f));
  p = __builtin_elementwise_fma(p, v, splat2(1.50140941f));
  f32x2 r = (p * x) * splat2(1.41421356f);
  if (w.x >= 5.0f) r.x = erfinv_big(x.x, w.x);   // rare (~0.34%/sample)
  if (w.y >= 5.0f) r.y = erfinv_big(x.y, w.y);
  return r;
}

__device__ __forceinline__ f32x2 bits_to_u2(unsigned b0, unsigned b1) {
  f32x2 f;
  f.x = __builtin_bit_cast(float, (b0 >> 9) | 0x3f800000u);
  f.y = __builtin_bit_cast(float, (b1 >> 9) | 0x3f800000u);
  f = f - splat2(1.0f);
  return __builtin_elementwise_fma(f, splat2(2.0f), splat2(-0.99999994f));
}

// ---------------- sampling (round-2 structure, best measured) ----------------
__global__ __launch_bounds__(256) void sample_kernel(
    const float* __restrict__ mu,      // ws
    const float* __restrict__ sigma,   // d_out + NC
    float* __restrict__ out0) {        // d_out
  int n    = blockIdx.x;
  int tid  = threadIdx.x;
  int lane = tid & 63, w = tid >> 6;
  __shared__ float pbuf[4][1024];

  int cb = n * 1000;
  float muv[16], sgv[16], prob[16];
#pragma unroll
  for (int j = 0; j < 16; j++) {
    int c = j * 64 + lane;
    bool val = (c < 1000);
    muv[j] = val ? mu[cb + c]    : 0.f;
    sgv[j] = val ? sigma[cb + c] : 0.f;
    prob[j] = 0.f;
  }

  f32x2 e[16];
#pragma unroll 1
  for (int it = 0; it < 4; it++) {
    int t = w * 4 + it;
    unsigned ib = (unsigned)(t * 4096000 + cb) + (unsigned)lane;
    f32x2 s = splat2(0.f);
#pragma unroll
    for (int j = 0; j < 16; j++) {
      unsigned i0 = ib + (unsigned)(j * 64);
      unsigned o0, o1;
      threefry(i0, i0 + H_HALF, o0, o1);
      f32x2 eps = normal2(bits_to_u2(o0, o1));
      f32x2 lg = __builtin_elementwise_fma(splat2(sgv[j]), eps, splat2(muv[j]));
      f32x2 ev;
      ev.x = __expf(lg.x);                       // sample t
      ev.y = __expf(lg.y);                       // sample t+16
      if (j == 15) {                             // classes >= 1000 are padding
        ev.x = (lane < 40) ? ev.x : 0.f;
        ev.y = (lane < 40) ? ev.y : 0.f;
      }
      e[j] = ev;
      s = s + ev;
    }
#pragma unroll
    for (int m = 1; m < 64; m <<= 1) {
      s.x += __shfl_xor(s.x, m, 64);
      s.y += __shfl_xor(s.y, m, 64);
    }
    float rA = 1.0f / s.x, rB = 1.0f / s.y;
#pragma unroll
    for (int j = 0; j < 16; j++)
      prob[j] = fmaf(e[j].x, rA, fmaf(e[j].y, rB, prob[j]));
  }

#pragma unroll
  for (int j = 0; j < 16; j++)
    pbuf[w][j * 64 + lane] = prob[j];
  __syncthreads();
#pragma unroll
  for (int k = 0; k < 4; k++) {
    int c = tid + k * 256;
    if (c < 1000) {
      float sm = pbuf[0][c] + pbuf[1][c] + pbuf[2][c] + pbuf[3][c];
      out0[cb + c] = __expf(sm * 0.03125f);
    }
  }
}

// ---------------- launch ----------------
extern "C" void kernel_launch(void* const* d_in, const int* in_sizes, int n_in,
                              void* d_out, int out_size, void* d_ws, size_t ws_size,
                              hipStream_t stream) {
  const float* x = (const float*)d_in[0];   // 4096*1024
  const float* W = (const float*)d_in[1];   // 2000*1024
  float* out = (float*)d_out;               // [mu_out | sigma], each 4096000

  unsigned short* xh = (unsigned short*)d_ws;                        //  8,388,608 B
  unsigned short* wh = (unsigned short*)((char*)d_ws + 8388608);     //  4,194,304 B
  float*          mu = (float*)((char*)d_ws + 12582912);             // 16,384,000 B
  float* sigma = out + NC_TOT;

  convert_kernel<<<3072, 256, 0, stream>>>(x, W, xh, wh);
  gemm_kernel<<<512, 256, 0, stream>>>(xh, wh, mu, sigma);
  sample_kernel<<<4096, 256, 0, stream>>>(mu, sigma, out);
}